// Round 1
// baseline (4034.123 us; speedup 1.0000x reference)
//
#include <hip/hip_runtime.h>
#include <cmath>

// Problem constants (from reference setup_inputs)
#define HSZ   1024   // H == E == A == 1024
#define SSZ   2048   // encoder length S
#define VSZ   50257  // vocab
#define BOUND 25
#define SOS   1
#define NPART 512    // logit argmax partials (= logit grid size)

// ---------------------------------------------------------------------------
// init: h0 = hidden[0]
// ---------------------------------------------------------------------------
__global__ __launch_bounds__(256) void init_kernel(const float* __restrict__ hidden,
                                                   float* __restrict__ h0) {
    int i = blockIdx.x * 256 + threadIdx.x;
    if (i < HSZ) h0[i] = hidden[i];
}

// ---------------------------------------------------------------------------
// eproj[s][a] = sum_k e[s][k] * W_e[a][k] + b_a[a]   (2048x1024x1024 fp32 GEMM)
// Tiled: BM=BN=64, BK=16, 256 threads, 4x4 micro-tile per thread. (unchanged)
// ---------------------------------------------------------------------------
#define BM 64
#define BN 64
#define BK 16
__global__ __launch_bounds__(256) void eproj_kernel(const float* __restrict__ e,
                                                    const float* __restrict__ We,
                                                    const float* __restrict__ b_a,
                                                    float* __restrict__ eproj) {
    __shared__ __align__(16) float As[BK][BM];
    __shared__ __align__(16) float Bs[BK][BN];
    const int tid = threadIdx.x;
    const int tx = tid & 15, ty = tid >> 4;
    const int arow0 = blockIdx.x * BM;   // s-tile
    const int brow0 = blockIdx.y * BN;   // a-tile
    const int lr = tid >> 2;             // 0..63
    const int lc = (tid & 3) * 4;        // 0,4,8,12

    float acc[4][4] = {};
    for (int k0 = 0; k0 < HSZ; k0 += BK) {
        float4 av = *(const float4*)&e [(size_t)(arow0 + lr) * HSZ + k0 + lc];
        float4 bv = *(const float4*)&We[(size_t)(brow0 + lr) * HSZ + k0 + lc];
        As[lc + 0][lr] = av.x; As[lc + 1][lr] = av.y;
        As[lc + 2][lr] = av.z; As[lc + 3][lr] = av.w;
        Bs[lc + 0][lr] = bv.x; Bs[lc + 1][lr] = bv.y;
        Bs[lc + 2][lr] = bv.z; Bs[lc + 3][lr] = bv.w;
        __syncthreads();
#pragma unroll
        for (int kk = 0; kk < BK; kk++) {
            float4 a4 = *(const float4*)&As[kk][ty * 4];
            float4 b4 = *(const float4*)&Bs[kk][tx * 4];
            float a[4] = {a4.x, a4.y, a4.z, a4.w};
            float b[4] = {b4.x, b4.y, b4.z, b4.w};
#pragma unroll
            for (int i = 0; i < 4; i++)
#pragma unroll
                for (int j = 0; j < 4; j++) acc[i][j] += a[i] * b[j];
        }
        __syncthreads();
    }
#pragma unroll
    for (int i = 0; i < 4; i++) {
        int s = arow0 + ty * 4 + i;
#pragma unroll
        for (int j = 0; j < 4; j++) {
            int a = brow0 + tx * 4 + j;
            eproj[(size_t)s * HSZ + a] = acc[i][j] + b_a[a];
        }
    }
}

// ---------------------------------------------------------------------------
// GRU cell, one block per hidden unit j. Folds the final argmax over the
// NPART logit partials at the head (all blocks redundantly; 4 KB L2-hot).
// float4 loads: thread t covers c = 4t..4t+3 (256*4 = 1024, one pass).
// ---------------------------------------------------------------------------
__global__ __launch_bounds__(256) void gru_kernel(const float* __restrict__ emb_table,
                                                  const float* __restrict__ W_ih,
                                                  const float* __restrict__ W_hh,
                                                  const float* __restrict__ b_ih,
                                                  const float* __restrict__ b_hh,
                                                  const float* __restrict__ h_old,
                                                  const float* __restrict__ pval,
                                                  const int* __restrict__ pidx,
                                                  int first,
                                                  float* __restrict__ h_new,
                                                  float* __restrict__ out_prev) {
    const int t = threadIdx.x;
    const int j = blockIdx.x;
    __shared__ float rv[256];
    __shared__ int ri[256];

    int word;
    if (!first) {
        float bv = -INFINITY; int bi = 0x7fffffff;
        for (int i = t; i < NPART; i += 256) {
            float v = pval[i]; int id = pidx[i];
            if (v > bv || (v == bv && id < bi)) { bv = v; bi = id; }
        }
        rv[t] = bv; ri[t] = bi;
        __syncthreads();
        for (int s2 = 128; s2 > 0; s2 >>= 1) {
            if (t < s2) {
                if (rv[t + s2] > rv[t] || (rv[t + s2] == rv[t] && ri[t + s2] < ri[t])) {
                    rv[t] = rv[t + s2]; ri[t] = ri[t + s2];
                }
            }
            __syncthreads();
        }
        word = ri[0];
        if (j == 0 && t == 0 && out_prev) *out_prev = (float)word;
    } else {
        word = SOS;
    }

    const float* __restrict__ x = emb_table + (size_t)word * HSZ;
    const int c = t * 4;
    float4 x4 = *(const float4*)&x[c];
    float4 h4 = *(const float4*)&h_old[c];
    float acc[6];
#pragma unroll
    for (int g = 0; g < 3; g++) {
        float4 wi = *(const float4*)&W_ih[(size_t)(g * HSZ + j) * HSZ + c];
        float4 wh = *(const float4*)&W_hh[(size_t)(g * HSZ + j) * HSZ + c];
        acc[g]     = wi.x * x4.x + wi.y * x4.y + wi.z * x4.z + wi.w * x4.w;
        acc[3 + g] = wh.x * h4.x + wh.y * h4.y + wh.z * h4.z + wh.w * h4.w;
    }
#pragma unroll
    for (int g = 0; g < 6; g++)
#pragma unroll
        for (int off = 32; off > 0; off >>= 1) acc[g] += __shfl_down(acc[g], off, 64);

    const int wave = t >> 6, lane = t & 63;
    __shared__ float wred[4][6];
    if (lane == 0) {
#pragma unroll
        for (int g = 0; g < 6; g++) wred[wave][g] = acc[g];
    }
    __syncthreads();
    if (t == 0) {
        float res[6];
#pragma unroll
        for (int g = 0; g < 6; g++)
            res[g] = wred[0][g] + wred[1][g] + wred[2][g] + wred[3][g];
        float ir = res[0] + b_ih[j];
        float iz = res[1] + b_ih[HSZ + j];
        float in_ = res[2] + b_ih[2 * HSZ + j];
        float hr = res[3] + b_hh[j];
        float hz = res[4] + b_hh[HSZ + j];
        float hn = res[5] + b_hh[2 * HSZ + j];
        float r = 1.f / (1.f + expf(-(ir + hr)));
        float z = 1.f / (1.f + expf(-(iz + hz)));
        float n = tanhf(in_ + r * hn);
        h_new[j] = (1.f - z) * n + z * h_old[j];
    }
}

// ---------------------------------------------------------------------------
// q[a] = sum_c W_q[a][c] * h[c]   (float4 + shfl reduce)
// ---------------------------------------------------------------------------
__global__ __launch_bounds__(256) void q_kernel(const float* __restrict__ W_q,
                                                const float* __restrict__ h,
                                                float* __restrict__ q) {
    const int a = blockIdx.x, t = threadIdx.x;
    const int c = t * 4;
    float4 wq = *(const float4*)&W_q[(size_t)a * HSZ + c];
    float4 h4 = *(const float4*)&h[c];
    float acc = wq.x * h4.x + wq.y * h4.y + wq.z * h4.z + wq.w * h4.w;
#pragma unroll
    for (int off = 32; off > 0; off >>= 1) acc += __shfl_down(acc, off, 64);
    const int wave = t >> 6, lane = t & 63;
    __shared__ float wred[4];
    if (lane == 0) wred[wave] = acc;
    __syncthreads();
    if (t == 0) q[a] = wred[0] + wred[1] + wred[2] + wred[3];
}

// ---------------------------------------------------------------------------
// s[k] = sum_a tanh(eproj[k][a] + q[a]) * v_a[a]; blocks 0..3 also zero ctx
// (consumed by attn_kernel atomics next launch).
// ---------------------------------------------------------------------------
__global__ __launch_bounds__(256) void score_kernel(const float* __restrict__ eproj,
                                                    const float* __restrict__ q,
                                                    const float* __restrict__ v_a,
                                                    float* __restrict__ s,
                                                    float* __restrict__ ctx) {
    const int k = blockIdx.x, t = threadIdx.x;
    if (k < 4) ctx[k * 256 + t] = 0.f;
    const int c = t * 4;
    float4 ev = *(const float4*)&eproj[(size_t)k * HSZ + c];
    float4 q4 = *(const float4*)&q[c];
    float4 v4 = *(const float4*)&v_a[c];
    float acc = tanhf(ev.x + q4.x) * v4.x + tanhf(ev.y + q4.y) * v4.y +
                tanhf(ev.z + q4.z) * v4.z + tanhf(ev.w + q4.w) * v4.w;
#pragma unroll
    for (int off = 32; off > 0; off >>= 1) acc += __shfl_down(acc, off, 64);
    const int wave = t >> 6, lane = t & 63;
    __shared__ float wred[4];
    if (lane == 0) wred[wave] = acc;
    __syncthreads();
    if (t == 0) s[k] = wred[0] + wred[1] + wred[2] + wred[3];
}

// ---------------------------------------------------------------------------
// attn: fused softmax + ctx. grid (32 k-chunks of 64, 4 col-chunks of 256).
// Every block redundantly computes softmax stats over all 2048 scores
// (8 KB read, L2-hot), then its own 64 w values; y==0 blocks write out_w.
// ctx[a] += sum_{k in chunk} w[k]*e[k][a] via atomics (ctx zeroed in score).
// ---------------------------------------------------------------------------
__global__ __launch_bounds__(256) void attn_kernel(const float* __restrict__ s,
                                                   const float* __restrict__ e,
                                                   float* __restrict__ ctx,
                                                   float* __restrict__ out_w) {
    const int t = threadIdx.x;
    const int kc = blockIdx.x;   // 0..31
    const int ac = blockIdx.y;   // 0..3
    __shared__ float red[256];

    float m = -INFINITY;
    for (int k = t; k < SSZ; k += 256) m = fmaxf(m, s[k]);
    red[t] = m;
    __syncthreads();
    for (int s2 = 128; s2 > 0; s2 >>= 1) {
        if (t < s2) red[t] = fmaxf(red[t], red[t + s2]);
        __syncthreads();
    }
    m = red[0];
    __syncthreads();

    float sum = 0.f;
    for (int k = t; k < SSZ; k += 256) sum += expf(s[k] - m);
    red[t] = sum;
    __syncthreads();
    for (int s2 = 128; s2 > 0; s2 >>= 1) {
        if (t < s2) red[t] += red[t + s2];
        __syncthreads();
    }
    float inv = 1.f / red[0];

    __shared__ float wch[64];
    if (t < 64) {
        float wv = expf(s[kc * 64 + t] - m) * inv;
        wch[t] = wv;
        if (ac == 0) out_w[kc * 64 + t] = wv;
    }
    __syncthreads();

    const int a = ac * 256 + t;
    float acc = 0.f;
#pragma unroll
    for (int k = 0; k < 64; k++)
        acc += wch[k] * e[(size_t)(kc * 64 + k) * HSZ + a];
    atomicAdd(&ctx[a], acc);
}

// ---------------------------------------------------------------------------
// logit partial argmax v2: wave-per-row, merge held in 32 VGPRs/lane,
// inner loop = pure float4 global loads (1 KB/instr, 8 KB in flight/wave).
// grid NPART=512 blocks x 4 waves = 2048 waves; row v = gw + 2048*i.
// ---------------------------------------------------------------------------
__global__ __launch_bounds__(256) void logit_kernel(const float* __restrict__ W_out,
                                                    const float* __restrict__ b_out,
                                                    const float* __restrict__ h,
                                                    const float* __restrict__ ctx,
                                                    float* __restrict__ pval,
                                                    int* __restrict__ pidx) {
    __shared__ float4 mrg[512];   // merge = [h, ctx], 2048 floats
    const int t = threadIdx.x;
    mrg[t]       = ((const float4*)h)[t];
    mrg[256 + t] = ((const float4*)ctx)[t];
    __syncthreads();

    const int wave = t >> 6, lane = t & 63;
    float4 m[8];
#pragma unroll
    for (int i = 0; i < 8; i++) m[i] = mrg[lane + 64 * i];

    const int gw = blockIdx.x * 4 + wave;   // 0..2047
    float best = -INFINITY;
    int bidx = 0x7fffffff;
    for (int v = gw; v < VSZ; v += 2048) {
        const float4* __restrict__ row = (const float4*)(W_out + (size_t)v * (2 * HSZ));
        float acc = 0.f;
#pragma unroll
        for (int i = 0; i < 8; i++) {
            float4 r = row[lane + 64 * i];
            acc += r.x * m[i].x + r.y * m[i].y + r.z * m[i].z + r.w * m[i].w;
        }
#pragma unroll
        for (int off = 32; off > 0; off >>= 1) acc += __shfl_down(acc, off, 64);
        if (lane == 0) {
            float logit = acc + b_out[v];
            if (logit > best) { best = logit; bidx = v; }   // v ascending → first-max kept
        }
    }
    __shared__ float bv[4];
    __shared__ int bi[4];
    if (lane == 0) { bv[wave] = best; bi[wave] = bidx; }
    __syncthreads();
    if (t == 0) {
        float B = bv[0]; int I = bi[0];
        for (int i = 1; i < 4; i++)
            if (bv[i] > B || (bv[i] == B && bi[i] < I)) { B = bv[i]; I = bi[i]; }
        pval[blockIdx.x] = B;
        pidx[blockIdx.x] = I;
    }
}

// ---------------------------------------------------------------------------
// epilogue: reduce last step's partials, write out[BOUND-1]
// ---------------------------------------------------------------------------
__global__ __launch_bounds__(256) void final_kernel(const float* __restrict__ pval,
                                                    const int* __restrict__ pidx,
                                                    float* __restrict__ out_word) {
    const int t = threadIdx.x;
    float bv = -INFINITY; int bi = 0x7fffffff;
    for (int i = t; i < NPART; i += 256) {
        float v = pval[i]; int id = pidx[i];
        if (v > bv || (v == bv && id < bi)) { bv = v; bi = id; }
    }
    __shared__ float rv[256];
    __shared__ int ri[256];
    rv[t] = bv; ri[t] = bi;
    __syncthreads();
    for (int s2 = 128; s2 > 0; s2 >>= 1) {
        if (t < s2) {
            if (rv[t + s2] > rv[t] || (rv[t + s2] == rv[t] && ri[t + s2] < ri[t])) {
                rv[t] = rv[t + s2]; ri[t] = ri[t + s2];
            }
        }
        __syncthreads();
    }
    if (t == 0) *out_word = (float)ri[0];
}

// ---------------------------------------------------------------------------
extern "C" void kernel_launch(void* const* d_in, const int* in_sizes, int n_in,
                              void* d_out, int out_size, void* d_ws, size_t ws_size,
                              hipStream_t stream) {
    const float* hidden     = (const float*)d_in[0];   // (1,1,1024)
    const float* embeddings = (const float*)d_in[1];   // (1,2048,1024)
    const float* emb_table  = (const float*)d_in[2];   // (50257,1024)
    const float* W_ih       = (const float*)d_in[3];   // (3072,1024)
    const float* W_hh       = (const float*)d_in[4];   // (3072,1024)
    const float* b_ih       = (const float*)d_in[5];   // (3072)
    const float* b_hh       = (const float*)d_in[6];   // (3072)
    const float* W_e        = (const float*)d_in[7];   // (1024,1024)
    const float* W_q        = (const float*)d_in[8];   // (1024,1024)
    const float* b_a        = (const float*)d_in[9];   // (1024)
    const float* v_a        = (const float*)d_in[10];  // (1024)
    const float* W_out      = (const float*)d_in[11];  // (50257,2048)
    const float* b_out      = (const float*)d_in[12];  // (50257)

    float* out = (float*)d_out;        // [0:25] words (as float), [25:] weights
    float* ws  = (float*)d_ws;

    // workspace layout (floats)
    float* eproj = ws;                          // 2048*1024
    float* h0    = ws + (size_t)SSZ * HSZ;      // 1024
    float* h1    = h0 + HSZ;                    // 1024
    float* qv    = h1 + HSZ;                    // 1024
    float* sc    = qv + HSZ;                    // 2048
    float* ctx   = sc + SSZ;                    // 1024
    float* pval  = ctx + HSZ;                   // NPART
    int*   pidx  = (int*)(pval + NPART);        // NPART

    init_kernel<<<4, 256, 0, stream>>>(hidden, h0);
    dim3 egrid(SSZ / BM, HSZ / BN);
    eproj_kernel<<<egrid, 256, 0, stream>>>(embeddings, W_e, b_a, eproj);

    for (int t = 0; t < BOUND; t++) {
        float* hold = (t & 1) ? h1 : h0;
        float* hnew = (t & 1) ? h0 : h1;
        gru_kernel<<<HSZ, 256, 0, stream>>>(emb_table, W_ih, W_hh, b_ih, b_hh,
                                            hold, pval, pidx, (t == 0) ? 1 : 0,
                                            hnew, (t > 0) ? out + (t - 1) : nullptr);
        q_kernel<<<HSZ, 256, 0, stream>>>(W_q, hnew, qv);
        score_kernel<<<SSZ, 256, 0, stream>>>(eproj, qv, v_a, sc, ctx);
        attn_kernel<<<dim3(32, 4), 256, 0, stream>>>(sc, embeddings, ctx,
                                                     out + BOUND + (size_t)t * SSZ);
        logit_kernel<<<NPART, 256, 0, stream>>>(W_out, b_out, hnew, ctx, pval, pidx);
    }
    final_kernel<<<1, 256, 0, stream>>>(pval, pidx, out + (BOUND - 1));
}

// Round 2
// 3255.982 us; speedup vs baseline: 1.2390x; 1.2390x over previous
//
#include <hip/hip_runtime.h>
#include <cmath>

// Problem constants (from reference setup_inputs)
#define HSZ   1024   // H == E == A == 1024
#define SSZ   2048   // encoder length S
#define VSZ   50257  // vocab
#define BOUND 25
#define SOS   1

// ---------------------------------------------------------------------------
// init: h0 = hidden[0], word = SOS
// ---------------------------------------------------------------------------
__global__ __launch_bounds__(256) void init_kernel(const float* __restrict__ hidden,
                                                   float* __restrict__ h0,
                                                   int* __restrict__ wordp) {
    int i = blockIdx.x * 256 + threadIdx.x;
    if (i < HSZ) h0[i] = hidden[i];
    if (i == 0) *wordp = SOS;
}

// ---------------------------------------------------------------------------
// eproj[s][a] = sum_k e[s][k] * W_e[a][k] + b_a[a]   (2048x1024x1024 fp32 GEMM)
// Tiled: BM=BN=64, BK=16, 256 threads, 4x4 micro-tile per thread.
// ---------------------------------------------------------------------------
#define BM 64
#define BN 64
#define BK 16
__global__ __launch_bounds__(256) void eproj_kernel(const float* __restrict__ e,
                                                    const float* __restrict__ We,
                                                    const float* __restrict__ b_a,
                                                    float* __restrict__ eproj) {
    __shared__ __align__(16) float As[BK][BM];
    __shared__ __align__(16) float Bs[BK][BN];
    const int tid = threadIdx.x;
    const int tx = tid & 15, ty = tid >> 4;
    const int arow0 = blockIdx.x * BM;   // s-tile
    const int brow0 = blockIdx.y * BN;   // a-tile
    // staging indices: each thread loads one float4 (64 rows x 16 cols)
    const int lr = tid >> 2;            // 0..63
    const int lc = (tid & 3) * 4;       // 0,4,8,12

    float acc[4][4] = {};
    for (int k0 = 0; k0 < HSZ; k0 += BK) {
        float4 av = *(const float4*)&e [(size_t)(arow0 + lr) * HSZ + k0 + lc];
        float4 bv = *(const float4*)&We[(size_t)(brow0 + lr) * HSZ + k0 + lc];
        As[lc + 0][lr] = av.x; As[lc + 1][lr] = av.y;
        As[lc + 2][lr] = av.z; As[lc + 3][lr] = av.w;
        Bs[lc + 0][lr] = bv.x; Bs[lc + 1][lr] = bv.y;
        Bs[lc + 2][lr] = bv.z; Bs[lc + 3][lr] = bv.w;
        __syncthreads();
#pragma unroll
        for (int kk = 0; kk < BK; kk++) {
            float4 a4 = *(const float4*)&As[kk][ty * 4];
            float4 b4 = *(const float4*)&Bs[kk][tx * 4];
            float a[4] = {a4.x, a4.y, a4.z, a4.w};
            float b[4] = {b4.x, b4.y, b4.z, b4.w};
#pragma unroll
            for (int i = 0; i < 4; i++)
#pragma unroll
                for (int j = 0; j < 4; j++) acc[i][j] += a[i] * b[j];
        }
        __syncthreads();
    }
#pragma unroll
    for (int i = 0; i < 4; i++) {
        int s = arow0 + ty * 4 + i;
#pragma unroll
        for (int j = 0; j < 4; j++) {
            int a = brow0 + tx * 4 + j;
            eproj[(size_t)s * HSZ + a] = acc[i][j] + b_a[a];
        }
    }
}

// ---------------------------------------------------------------------------
// GRU cell: one block per hidden unit j. 6 dot products of length 1024.
// (Round-0 verbatim)
// ---------------------------------------------------------------------------
__global__ __launch_bounds__(256) void gru_kernel(const float* __restrict__ emb_table,
                                                  const float* __restrict__ W_ih,
                                                  const float* __restrict__ W_hh,
                                                  const float* __restrict__ b_ih,
                                                  const float* __restrict__ b_hh,
                                                  const float* __restrict__ h_old,
                                                  const int* __restrict__ wordp,
                                                  float* __restrict__ h_new) {
    const int j = blockIdx.x;       // 0..1023
    const int t = threadIdx.x;      // 256
    const int word = *wordp;
    const float* __restrict__ x = emb_table + (size_t)word * HSZ;

    float acc[6] = {0.f, 0.f, 0.f, 0.f, 0.f, 0.f};
    for (int c = t; c < HSZ; c += 256) {
        float xv = x[c], hv = h_old[c];
#pragma unroll
        for (int g = 0; g < 3; g++) {
            acc[g]     += W_ih[(size_t)(g * HSZ + j) * HSZ + c] * xv;
            acc[3 + g] += W_hh[(size_t)(g * HSZ + j) * HSZ + c] * hv;
        }
    }
    __shared__ float red[256];
    __shared__ float res[6];
    for (int g = 0; g < 6; g++) {
        red[t] = acc[g];
        __syncthreads();
        for (int s2 = 128; s2 > 0; s2 >>= 1) {
            if (t < s2) red[t] += red[t + s2];
            __syncthreads();
        }
        if (t == 0) res[g] = red[0];
        __syncthreads();
    }
    if (t == 0) {
        float ir = res[0] + b_ih[j];
        float iz = res[1] + b_ih[HSZ + j];
        float in_ = res[2] + b_ih[2 * HSZ + j];
        float hr = res[3] + b_hh[j];
        float hz = res[4] + b_hh[HSZ + j];
        float hn = res[5] + b_hh[2 * HSZ + j];
        float r = 1.f / (1.f + expf(-(ir + hr)));
        float z = 1.f / (1.f + expf(-(iz + hz)));
        float n = tanhf(in_ + r * hn);
        h_new[j] = (1.f - z) * n + z * h_old[j];
    }
}

// ---------------------------------------------------------------------------
// q[a] = sum_c W_q[a][c] * h[c]   (Round-0 verbatim)
// ---------------------------------------------------------------------------
__global__ __launch_bounds__(256) void q_kernel(const float* __restrict__ W_q,
                                                const float* __restrict__ h,
                                                float* __restrict__ q) {
    const int a = blockIdx.x, t = threadIdx.x;
    float acc = 0.f;
    for (int c = t; c < HSZ; c += 256) acc += W_q[(size_t)a * HSZ + c] * h[c];
    __shared__ float red[256];
    red[t] = acc;
    __syncthreads();
    for (int s2 = 128; s2 > 0; s2 >>= 1) {
        if (t < s2) red[t] += red[t + s2];
        __syncthreads();
    }
    if (t == 0) q[a] = red[0];
}

// ---------------------------------------------------------------------------
// s[k] = sum_a tanh(eproj[k][a] + q[a]) * v_a[a]   (Round-0 verbatim)
// ---------------------------------------------------------------------------
__global__ __launch_bounds__(256) void score_kernel(const float* __restrict__ eproj,
                                                    const float* __restrict__ q,
                                                    const float* __restrict__ v_a,
                                                    float* __restrict__ s) {
    const int k = blockIdx.x, t = threadIdx.x;
    float acc = 0.f;
    for (int c = t; c < HSZ; c += 256)
        acc += tanhf(eproj[(size_t)k * HSZ + c] + q[c]) * v_a[c];
    __shared__ float red[256];
    red[t] = acc;
    __syncthreads();
    for (int s2 = 128; s2 > 0; s2 >>= 1) {
        if (t < s2) red[t] += red[t + s2];
        __syncthreads();
    }
    if (t == 0) s[k] = red[0];
}

// ---------------------------------------------------------------------------
// softmax over S=2048; writes normalized w to ws and to d_out; zeros ctx.
// (Round-0 verbatim)
// ---------------------------------------------------------------------------
__global__ __launch_bounds__(256) void softmax_kernel(const float* __restrict__ s,
                                                      float* __restrict__ w,
                                                      float* __restrict__ ctx,
                                                      float* __restrict__ out_w) {
    const int t = threadIdx.x;
    __shared__ float red[256];
    float m = -INFINITY;
    for (int k = t; k < SSZ; k += 256) m = fmaxf(m, s[k]);
    red[t] = m;
    __syncthreads();
    for (int s2 = 128; s2 > 0; s2 >>= 1) {
        if (t < s2) red[t] = fmaxf(red[t], red[t + s2]);
        __syncthreads();
    }
    m = red[0];
    __syncthreads();
    float sum = 0.f;
    for (int k = t; k < SSZ; k += 256) {
        float ev = expf(s[k] - m);
        w[k] = ev;
        sum += ev;
    }
    red[t] = sum;
    __syncthreads();
    for (int s2 = 128; s2 > 0; s2 >>= 1) {
        if (t < s2) red[t] += red[t + s2];
        __syncthreads();
    }
    float inv = 1.f / red[0];
    for (int k = t; k < SSZ; k += 256) {
        float wv = w[k] * inv;
        w[k] = wv;
        out_w[k] = wv;
    }
    for (int c = t; c < HSZ; c += 256) ctx[c] = 0.f;   // for ctx_kernel atomics
}

// ---------------------------------------------------------------------------
// ctx[a] += sum_{k in chunk} w[k] * e[k][a]  (split-K with atomics)
// grid: (32 k-chunks of 64) x (4 column chunks of 256)   (Round-0 verbatim)
// ---------------------------------------------------------------------------
__global__ __launch_bounds__(256) void ctx_kernel(const float* __restrict__ e,
                                                  const float* __restrict__ w,
                                                  float* __restrict__ ctx) {
    const int a = blockIdx.y * 256 + threadIdx.x;
    const int k0 = blockIdx.x * 64;
    float acc = 0.f;
    for (int k = k0; k < k0 + 64; k++) acc += w[k] * e[(size_t)k * HSZ + a];
    atomicAdd(&ctx[a], acc);
}

// ---------------------------------------------------------------------------
// logit partial argmax v2 (THE ONLY CHANGE vs Round 0):
// merge held in 32 VGPRs/lane; inner loop = pure float4 global loads
// (64 lanes x 16 B = 1 KB/instr, 8 KB in flight per wave).
// Grid UNCHANGED from Round 0: 1024 blocks x 4 waves = 4096 waves
// (4-5 blocks/CU, 16+ waves/CU); row v = gw + 4096*i, ~12.3 rows/wave.
// ---------------------------------------------------------------------------
__global__ __launch_bounds__(256) void logit_kernel(const float* __restrict__ W_out,
                                                    const float* __restrict__ b_out,
                                                    const float* __restrict__ h,
                                                    const float* __restrict__ ctx,
                                                    float* __restrict__ pval,
                                                    int* __restrict__ pidx) {
    __shared__ float4 mrg[512];   // merge = [h, ctx], 2048 floats
    const int t = threadIdx.x;
    mrg[t]       = ((const float4*)h)[t];
    mrg[256 + t] = ((const float4*)ctx)[t];
    __syncthreads();

    const int wave = t >> 6, lane = t & 63;
    float4 m[8];
#pragma unroll
    for (int i = 0; i < 8; i++) m[i] = mrg[lane + 64 * i];

    const int gw = blockIdx.x * 4 + wave;    // 0..4095
    float best = -INFINITY;
    int bidx = 0x7fffffff;
    for (int v = gw; v < VSZ; v += 4096) {
        const float4* __restrict__ row = (const float4*)(W_out + (size_t)v * (2 * HSZ));
        float acc = 0.f;
#pragma unroll
        for (int i = 0; i < 8; i++) {
            float4 r = row[lane + 64 * i];
            acc += r.x * m[i].x + r.y * m[i].y + r.z * m[i].z + r.w * m[i].w;
        }
#pragma unroll
        for (int off = 32; off > 0; off >>= 1) acc += __shfl_down(acc, off, 64);
        if (lane == 0) {
            float logit = acc + b_out[v];
            if (logit > best) { best = logit; bidx = v; }   // v ascending → first-max kept
        }
    }
    __shared__ float bv[4];
    __shared__ int bi[4];
    if (lane == 0) { bv[wave] = best; bi[wave] = bidx; }
    __syncthreads();
    if (t == 0) {
        float B = bv[0]; int I = bi[0];
        for (int i = 1; i < 4; i++)
            if (bv[i] > B || (bv[i] == B && bi[i] < I)) { B = bv[i]; I = bi[i]; }
        pval[blockIdx.x] = B;
        pidx[blockIdx.x] = I;
    }
}

// ---------------------------------------------------------------------------
// final argmax over 1024 block partials; writes word (int to ws, float to out)
// (Round-0 verbatim)
// ---------------------------------------------------------------------------
__global__ __launch_bounds__(256) void argmax_final_kernel(const float* __restrict__ pval,
                                                           const int* __restrict__ pidx,
                                                           int* __restrict__ wordp,
                                                           float* __restrict__ out_word) {
    const int t = threadIdx.x;
    float best = -INFINITY;
    int bidx = 0x7fffffff;
    for (int i = t; i < 1024; i += 256) {
        float v = pval[i];
        int id = pidx[i];
        if (v > best || (v == best && id < bidx)) { best = v; bidx = id; }
    }
    __shared__ float bv[256];
    __shared__ int bi[256];
    bv[t] = best; bi[t] = bidx;
    __syncthreads();
    for (int s2 = 128; s2 > 0; s2 >>= 1) {
        if (t < s2) {
            if (bv[t + s2] > bv[t] || (bv[t + s2] == bv[t] && bi[t + s2] < bi[t])) {
                bv[t] = bv[t + s2];
                bi[t] = bi[t + s2];
            }
        }
        __syncthreads();
    }
    if (t == 0) {
        *wordp = bi[0];
        *out_word = (float)bi[0];
    }
}

// ---------------------------------------------------------------------------
extern "C" void kernel_launch(void* const* d_in, const int* in_sizes, int n_in,
                              void* d_out, int out_size, void* d_ws, size_t ws_size,
                              hipStream_t stream) {
    const float* hidden     = (const float*)d_in[0];   // (1,1,1024)
    const float* embeddings = (const float*)d_in[1];   // (1,2048,1024)
    const float* emb_table  = (const float*)d_in[2];   // (50257,1024)
    const float* W_ih       = (const float*)d_in[3];   // (3072,1024)
    const float* W_hh       = (const float*)d_in[4];   // (3072,1024)
    const float* b_ih       = (const float*)d_in[5];   // (3072)
    const float* b_hh       = (const float*)d_in[6];   // (3072)
    const float* W_e        = (const float*)d_in[7];   // (1024,1024)
    const float* W_q        = (const float*)d_in[8];   // (1024,1024)
    const float* b_a        = (const float*)d_in[9];   // (1024)
    const float* v_a        = (const float*)d_in[10];  // (1024)
    const float* W_out      = (const float*)d_in[11];  // (50257,2048)
    const float* b_out      = (const float*)d_in[12];  // (50257)

    float* out = (float*)d_out;        // [0:25] words (as float), [25:] weights
    float* ws  = (float*)d_ws;

    // workspace layout (floats)
    float* eproj = ws;                         // 2048*1024
    float* h0    = ws + (size_t)SSZ * HSZ;     // 1024
    float* h1    = h0 + HSZ;                   // 1024
    float* q     = h1 + HSZ;                   // 1024
    float* sc    = q + HSZ;                    // 2048
    float* w     = sc + SSZ;                   // 2048
    float* ctx   = w + SSZ;                    // 1024
    float* pval  = ctx + HSZ;                  // 1024
    int*   pidx  = (int*)(pval + 1024);        // 1024
    int*   wordp = (int*)(pval + 2048);        // 1

    init_kernel<<<4, 256, 0, stream>>>(hidden, h0, wordp);
    dim3 egrid(SSZ / BM, HSZ / BN);
    eproj_kernel<<<egrid, 256, 0, stream>>>(embeddings, W_e, b_a, eproj);

    for (int t = 0; t < BOUND; t++) {
        float* hold = (t & 1) ? h1 : h0;
        float* hnew = (t & 1) ? h0 : h1;
        gru_kernel<<<HSZ, 256, 0, stream>>>(emb_table, W_ih, W_hh, b_ih, b_hh,
                                            hold, wordp, hnew);
        q_kernel<<<HSZ, 256, 0, stream>>>(W_q, hnew, q);
        score_kernel<<<SSZ, 256, 0, stream>>>(eproj, q, v_a, sc);
        softmax_kernel<<<1, 256, 0, stream>>>(sc, w, ctx, out + BOUND + (size_t)t * SSZ);
        ctx_kernel<<<dim3(32, 4), 256, 0, stream>>>(embeddings, w, ctx);
        logit_kernel<<<1024, 256, 0, stream>>>(W_out, b_out, hnew, ctx, pval, pidx);
        argmax_final_kernel<<<1, 256, 0, stream>>>(pval, pidx, wordp, out + t);
    }
}